// Round 11
// baseline (211.478 us; speedup 1.0000x reference)
//
#include <hip/hip_runtime.h>

// MultipleKmeans: T=16384 frames, E=1024, M=8 models, K=512 clusters.
// Round 15: R14 (nontemporal A/out hints on the R10 best schedule), with
// the compile fix: __builtin_nontemporal_* requires ext_vector pointers,
// not HIP_vector_type. All nt accesses go through f32x4.
// Theory: model-m blocks live on XCD m (grid (M,80), id%8=m); the 1MB B
// panel should be L2-resident but the 8MB single-use A stream through the
// same 4MB XCD L2 evicts it -> B refills at L3 latency (~600cy) which the
// depth-8 ring (~300cy cover) can't hide. NT A-loads keep the L2 for B.
// Totals fact (R0-R13): total ~= k_dist + 113us; k_dist is the 1:1 lever.
//
// ws layout (<=100416 B):
//   [     0, 32768): double csq64[M*K]
//   [ 32768, 34816): int    hist[64][8]
//   [ 34816, 34880): int    offs[9]
//   [ 34880,100416): int    order[T]

#define T_FRAMES 16384
#define E_DIM    1024
#define M_MODELS 8
#define K_CLUST  512

#define FPB 32     // frames per k_dist block
#define NCH 8      // K chunks of 128

typedef __bf16 bf16x8 __attribute__((ext_vector_type(8)));
typedef float  floatx16 __attribute__((ext_vector_type(16)));
typedef float  f32x4 __attribute__((ext_vector_type(4)));

__device__ __forceinline__ bf16x8 cvt8(const float4 a, const float4 b) {
  bf16x8 h;
  h[0] = (__bf16)a.x; h[1] = (__bf16)a.y; h[2] = (__bf16)a.z; h[3] = (__bf16)a.w;
  h[4] = (__bf16)b.x; h[5] = (__bf16)b.y; h[6] = (__bf16)b.z; h[7] = (__bf16)b.w;
  return h;
}

__device__ __forceinline__ bf16x8 cvt8v(const f32x4 a, const f32x4 b) {
  bf16x8 h;
  h[0] = (__bf16)a[0]; h[1] = (__bf16)a[1]; h[2] = (__bf16)a[2]; h[3] = (__bf16)a[3];
  h[4] = (__bf16)b[0]; h[5] = (__bf16)b[1]; h[6] = (__bf16)b[2]; h[7] = (__bf16)b[3];
  return h;
}

// ------- K0: cent fp32 -> swizzled bf16 (+csq64) + hist (blocks 0..63) -----
__global__ __launch_bounds__(256) void k_cvt(const float* __restrict__ cent,
                                             float* __restrict__ out,
                                             double* __restrict__ csq64,
                                             const int* __restrict__ midx,
                                             int* __restrict__ hist) {
  const int b = blockIdx.x;              // 512 blocks
  const int m = b >> 6;
  const int cg = (b >> 2) & 15;
  const int q = b & 3;
  const int tid = threadIdx.x;
  const int ci = tid & 31;
  const int t8 = tid >> 5;               // 0..7
  const int gk0 = q * 32 + t8 * 4;
  const int B32 = (m * 16 + cg) * 32;
  const float* src = cent + ((size_t)(m * K_CLUST + cg * 32 + ci)) * E_DIM;
  double ss = 0.0;
#pragma unroll
  for (int j = 0; j < 4; ++j) {
    const int gk = gk0 + j;
    const float4 a = *(const float4*)(src + gk * 8);
    const float4 bb = *(const float4*)(src + gk * 8 + 4);
    ss += (double)a.x * a.x + (double)a.y * a.y + (double)a.z * a.z +
          (double)a.w * a.w + (double)bb.x * bb.x + (double)bb.y * bb.y +
          (double)bb.z * bb.z + (double)bb.w * bb.w;
    const size_t foff = (size_t)(B32 + (gk >> 2)) * 1024 + 512 +
                        ((gk & 3) * 32 + ci) * 4;
    *(bf16x8*)(out + foff) = cvt8(a, bb);
  }
  __shared__ double csq_l[32][8];
  csq_l[ci][t8] = ss;
  __syncthreads();
  if (tid < 32) {
    double s = 0.0;
#pragma unroll
    for (int t = 0; t < 8; ++t) s += csq_l[tid][t];
    atomicAdd(&csq64[m * K_CLUST + cg * 32 + tid], s);
  }
  // ---- fused per-segment model histogram (blocks 0..63 only) ----
  if (b < 64) {
    __shared__ int h[M_MODELS * 33];
    for (int i = tid; i < M_MODELS * 33; i += 256) h[i] = 0;
    __syncthreads();
    const int mm = midx[b * 256 + tid];
    atomicAdd(&h[mm * 33 + (tid & 31)], 1);
    __syncthreads();
    if (tid < M_MODELS) {
      int s = 0;
      for (int j = 0; j < 32; ++j) s += h[tid * 33 + j];
      hist[b * M_MODELS + tid] = s;
    }
  }
}

// ---------------- K2: scatter frames into per-model buckets ----------------
__global__ __launch_bounds__(256) void k_scatter(const int* __restrict__ midx,
                                                 const int* __restrict__ hist,
                                                 int* __restrict__ order,
                                                 int* __restrict__ offs) {
  __shared__ int h2[64 * M_MODELS];
  __shared__ int cur[M_MODELS];
  const int tid = threadIdx.x;
  h2[tid] = hist[tid];
  h2[tid + 256] = hist[tid + 256];
  __syncthreads();
  if (tid < M_MODELS) {
    int tot_before = 0;
    for (int mp = 0; mp < tid; ++mp)
      for (int b = 0; b < 64; ++b) tot_before += h2[b * M_MODELS + mp];
    int prior = 0;
    for (int b = 0; b < (int)blockIdx.x; ++b) prior += h2[b * M_MODELS + tid];
    cur[tid] = tot_before + prior;
  }
  if (blockIdx.x == 0 && tid <= M_MODELS) {
    int o = 0;
    for (int mp = 0; mp < tid; ++mp)
      for (int b = 0; b < 64; ++b) o += h2[b * M_MODELS + mp];
    offs[tid] = o;
  }
  __syncthreads();
  const int f = blockIdx.x * 256 + tid;
  const int pos = atomicAdd(&cur[midx[f]], 1);
  order[pos] = f;
}

// ---------------- K3: fused scores + argmin + recheck -> code/output -------
// Block: 8 waves (512 thr), tile = 32 frames x 512 cols; wave w -> cols
// [w*64, w*64+64). acc: 2 x 32x32 tiles. A: LDS chunks of 128 k, double-
// buffered (16 KB), A loads NONTEMPORAL (keep XCD L2 for the B panel).
// B: swizzled bf16 (d_out rows 0..4095 high halves), depth-8 ring.
// grid = (M, 80): linear id % 8 == m -> per-model XCD affinity.
// Resolution: t>=4096 -> nontemporal direct row write; t<4096 -> park code.
__global__ __launch_bounds__(512, 2) void k_dist(const float* __restrict__ emb,
                                                 const float* __restrict__ cent,
                                                 const double* __restrict__ csq64,
                                                 const int* __restrict__ order,
                                                 const int* __restrict__ offs,
                                                 float* __restrict__ out) {
  const int m = blockIdx.x;
  const int o0 = offs[m];
  const int cnt = offs[m + 1] - o0;
  const int start = blockIdx.y * FPB;
  if (start >= cnt) return;
  const int nvalid = min(FPB, cnt - start);

  __shared__ __align__(16) __bf16 A_l[2 * 16 * FPB * 8];  // 16 KB
  __shared__ int rows_l[FPB];
  __shared__ float wmin_s[8][FPB];
  __shared__ int wcol_s[8][FPB];
  __shared__ float gmin_s[FPB];
  __shared__ int cnt_s[FPB];
  __shared__ int cand_s[FPB][32];

  const int tid = threadIdx.x;
  const int l = tid & 63;
  const int w = tid >> 6;          // 0..7
  const int ln = l & 31;
  const int lh = l >> 5;

  if (tid < FPB) rows_l[tid] = order[o0 + start + min(tid, nvalid - 1)];
  __syncthreads();

  // A staging role: thread -> row (tid&31), k-granule (tid>>5), 1 granule each
  const int s_row = tid & 31;
  const int s_g = tid >> 5;                      // 0..15
  const f32x4* emb4 = (const f32x4*)emb;
  const size_t arow4 = (size_t)rows_l[s_row] * (E_DIM / 4);

  f32x4 pa[2];
  pa[0] = __builtin_nontemporal_load(&emb4[arow4 + s_g * 2 + 0]);
  pa[1] = __builtin_nontemporal_load(&emb4[arow4 + s_g * 2 + 1]);
  *(bf16x8*)(A_l + ((s_g)*FPB + s_row) * 8) = cvt8v(pa[0], pa[1]);

  // B base pointers (swizzled bf16 region in d_out); wave w -> cg {2w, 2w+1}
  const char* bbase[2];
#pragma unroll
  for (int ct = 0; ct < 2; ++ct) {
    const int cg = w * 2 + ct;
    bbase[ct] = (const char*)out + (size_t)(m * 16 + cg) * 131072 + 2048 + l * 16;
  }
#define LOADB(ct, kb) (*(const bf16x8*)(bbase[ct] + (((kb) >> 1) << 12) + (((kb) & 1) << 10)))

  bf16x8 bR[8][2];                               // depth-8 ring
#pragma unroll
  for (int d = 0; d < 8; ++d)
#pragma unroll
    for (int ct = 0; ct < 2; ++ct) bR[d][ct] = LOADB(ct, d);

  floatx16 acc[2] = {};

  for (int c = 0; c < NCH; ++c) {
    __syncthreads();                             // A buf (c&1) ready
    const int buf = (c & 1) * 16;
    if (c + 1 < NCH) {
      pa[0] = __builtin_nontemporal_load(&emb4[arow4 + (c + 1) * 32 + s_g * 2 + 0]);
      pa[1] = __builtin_nontemporal_load(&emb4[arow4 + (c + 1) * 32 + s_g * 2 + 1]);
    }
#pragma unroll
    for (int jj = 0; jj < 8; ++jj) {
      const int kb = c * 8 + jj;
      const int p = kb & 7;
      const bf16x8 a0 = *(const bf16x8*)(A_l + ((buf + jj * 2 + lh) * FPB + ln) * 8);
      acc[0] = __builtin_amdgcn_mfma_f32_32x32x16_bf16(a0, bR[p][0], acc[0], 0, 0, 0);
      acc[1] = __builtin_amdgcn_mfma_f32_32x32x16_bf16(a0, bR[p][1], acc[1], 0, 0, 0);
      if (kb + 8 < 64) {
        bR[p][0] = LOADB(0, kb + 8);
        bR[p][1] = LOADB(1, kb + 8);
      }
    }
    if (c + 1 < NCH) {                           // write other buffer
      const int nbuf = ((c + 1) & 1) * 16;
      *(bf16x8*)(A_l + ((nbuf + s_g) * FPB + s_row) * 8) = cvt8v(pa[0], pa[1]);
    }
  }
#undef LOADB

  // ---- per-wave argmin (scores s = csq - 2*dot stay in regs) ----
  float cs[2];
#pragma unroll
  for (int ct = 0; ct < 2; ++ct)
    cs[ct] = (float)csq64[m * K_CLUST + w * 64 + ct * 32 + ln];

#pragma unroll
  for (int r = 0; r < 16; ++r) {
    const int fr = (r & 3) + 8 * (r >> 2) + 4 * lh;
    float bm = cs[0] - 2.0f * acc[0][r];
    int bc = w * 64 + ln;
    {
      const float s = cs[1] - 2.0f * acc[1][r];
      if (s < bm) { bm = s; bc = w * 64 + 32 + ln; }
    }
#pragma unroll
    for (int sh = 1; sh <= 16; sh <<= 1) {       // reduce within lane-half
      const float om = __shfl_xor(bm, sh, 64);
      const int oc = __shfl_xor(bc, sh, 64);
      if (om < bm || (om == bm && oc < bc)) { bm = om; bc = oc; }
    }
    if (ln == 0) { wmin_s[w][fr] = bm; wcol_s[w][fr] = bc; }
  }
  __syncthreads();

  if (tid < FPB) {                               // cross-wave min
    float g = wmin_s[0][tid];
    int gc = wcol_s[0][tid];
#pragma unroll
    for (int w2 = 1; w2 < 8; ++w2) {
      const float v = wmin_s[w2][tid];
      const int vc = wcol_s[w2][tid];
      if (v < g || (v == g && vc < gc)) { g = v; gc = vc; }
    }
    gmin_s[tid] = g;
    cnt_s[tid] = 0;
  }
  __syncthreads();

  // ---- candidate collection within eps = 3.0 ----
#pragma unroll
  for (int r = 0; r < 16; ++r) {
    const int fr = (r & 3) + 8 * (r >> 2) + 4 * lh;
    const float thr = gmin_s[fr] + 3.0f;
#pragma unroll
    for (int ct = 0; ct < 2; ++ct) {
      const float s = cs[ct] - 2.0f * acc[ct][r];
      if (s < thr) {
        const int ix = atomicAdd(&cnt_s[fr], 1);
        if (ix < 32) cand_s[fr][ix] = w * 64 + ct * 32 + ln;
      }
    }
  }
  __syncthreads();

  // ---- resolution: wave w -> frames w*4 .. w*4+3; exact fp64 recheck ----
  for (int i = 0; i < 4; ++i) {
    const int f = w * 4 + i;
    const int t = rows_l[f];
    const int n = min(cnt_s[f], 32);
    int code;
    if (n == 1) {
      code = cand_s[f][0];
    } else {
      f32x4 xv[4];
#pragma unroll
      for (int q = 0; q < 4; ++q)
        xv[q] = __builtin_nontemporal_load(&emb4[(size_t)t * (E_DIM / 4) + q * 64 + l]);
      double bd = 1e300;
      int bi = 1 << 30;
      for (int j = 0; j < n; ++j) {
        const int cc = cand_s[f][j];
        const f32x4* crow4 = (const f32x4*)(cent + ((size_t)(m * K_CLUST + cc)) * E_DIM);
        double s = 0.0;
#pragma unroll
        for (int q = 0; q < 4; ++q) {
          const f32x4 cv = crow4[q * 64 + l];
          s += (double)xv[q][0] * cv[0] + (double)xv[q][1] * cv[1] +
               (double)xv[q][2] * cv[2] + (double)xv[q][3] * cv[3];
        }
#pragma unroll
        for (int sh = 32; sh >= 1; sh >>= 1) s += __shfl_xor(s, sh, 64);
        const double d = csq64[m * K_CLUST + cc] - 2.0 * s;
        if (d < bd || (d == bd && cc < bi)) { bd = d; bi = cc; }
      }
      code = bi;
    }
    if (t >= 4096) {
      // rows >= 4096 never hold B panels: write the row directly (nt store,
      // never re-read on GPU). cent row read stays cached (reused).
      const f32x4* crow = (const f32x4*)(cent + ((size_t)(m * K_CLUST + code)) * E_DIM);
      f32x4* drow = (f32x4*)(out + (size_t)t * E_DIM);
#pragma unroll
      for (int q = 0; q < 4; ++q)
        __builtin_nontemporal_store(crow[q * 64 + l], &drow[q * 64 + l]);
    } else if (l == 0) {
      *(int*)(out + (size_t)t * E_DIM) = code;   // col 0: no B overlap
    }
  }
}

// ---------------- K4: expand parked codes (t < 4096) -> output rows --------
__global__ __launch_bounds__(256) void k_gather(const float* __restrict__ cent,
                                                const int* __restrict__ midx,
                                                float* __restrict__ out) {
  const int t = blockIdx.x * 4 + (threadIdx.x >> 6);   // t in [0, 4096)
  const int l = threadIdx.x & 63;
  float* drow = out + (size_t)t * E_DIM;
  const int code = *(const int*)drow;            // read before overwrite (dep-ordered)
  const int m = midx[t];
  const f32x4* src = (const f32x4*)(cent + ((size_t)(m * K_CLUST + code)) * E_DIM);
  f32x4* dst = (f32x4*)drow;
#pragma unroll
  for (int q = 0; q < 4; ++q)
    __builtin_nontemporal_store(src[q * 64 + l], &dst[q * 64 + l]);
}

extern "C" void kernel_launch(void* const* d_in, const int* in_sizes, int n_in,
                              void* d_out, int out_size, void* d_ws, size_t ws_size,
                              hipStream_t stream) {
  const float* emb = (const float*)d_in[0];     // [1,T,E] fp32
  const float* cent = (const float*)d_in[1];    // [M,K,E] fp32
  const int* midx = (const int*)d_in[2];        // [T] int32
  float* out = (float*)d_out;                   // [1,T,E] fp32

  char* ws = (char*)d_ws;                       // ~100 KB
  double* csq64 = (double*)(ws + 0);
  int* hist = (int*)(ws + 32768);
  int* offs = (int*)(ws + 34816);
  int* order = (int*)(ws + 34880);

  (void)hipMemsetAsync(csq64, 0, M_MODELS * K_CLUST * sizeof(double), stream);
  hipLaunchKernelGGL(k_cvt, dim3(512), dim3(256), 0, stream,
                     cent, out, csq64, midx, hist);
  hipLaunchKernelGGL(k_scatter, dim3(64), dim3(256), 0, stream, midx, hist, order, offs);
  hipLaunchKernelGGL(k_dist, dim3(M_MODELS, 80), dim3(512), 0, stream,
                     emb, cent, csq64, order, offs, out);
  hipLaunchKernelGGL(k_gather, dim3(4096 / 4), dim3(256), 0, stream,
                     cent, midx, out);
}

// Round 12
// 194.131 us; speedup vs baseline: 1.0894x; 1.0894x over previous
//
#include <hip/hip_runtime.h>

// MultipleKmeans: T=16384 frames, E=1024, M=8 models, K=512 clusters.
// Round 16: COALESCED A-GATHER. R12's probe put the no-B-refill core at
// ~30us; the only unmodeled cost in it is the A staging, whose mapping
// (s_row=tid&31) makes adjacent lanes read 16B from rows 4KB apart ->
// ~64 scattered 64B-line requests per wave instr; 64MB at HBM random-64B
// (~2.5TB/s) ~= 26-30us = the probe. Same anti-pattern in k_cvt.
// Fix: transpose the thread mapping. k_dist: s_row=tid>>4, s_o=tid&15 ->
// 16 lanes read one row's 512B chunk contiguously; LDS granule stride
// padded 32->33 so the transposed ds_write is 2-way (free) not 16-way.
// k_cvt: row=tid>>3, o=tid&7 (128B contiguous per thread).
// Everything else = R10 exactly (best 196.4; NT hints of R15 reverted —
// they regressed). Depth-8 B ring, NCH=8, direct-write epilogue.
//
// ws layout (<=100416 B):
//   [     0, 32768): double csq64[M*K]
//   [ 32768, 34816): int    hist[64][8]
//   [ 34816, 34880): int    offs[9]
//   [ 34880,100416): int    order[T]

#define T_FRAMES 16384
#define E_DIM    1024
#define M_MODELS 8
#define K_CLUST  512

#define FPB 32     // frames per k_dist block
#define NCH 8      // K chunks of 128
#define ROWP 33    // padded LDS granule stride (rows) -> 2-way write aliasing

typedef __bf16 bf16x8 __attribute__((ext_vector_type(8)));
typedef float  floatx16 __attribute__((ext_vector_type(16)));

__device__ __forceinline__ bf16x8 cvt8(const float4 a, const float4 b) {
  bf16x8 h;
  h[0] = (__bf16)a.x; h[1] = (__bf16)a.y; h[2] = (__bf16)a.z; h[3] = (__bf16)a.w;
  h[4] = (__bf16)b.x; h[5] = (__bf16)b.y; h[6] = (__bf16)b.z; h[7] = (__bf16)b.w;
  return h;
}

// ------- K0: cent fp32 -> swizzled bf16 (+csq64) + hist (blocks 0..63) -----
// Coalesced remap: 8 threads per cluster row, each reading 128B contiguous.
__global__ __launch_bounds__(256) void k_cvt(const float* __restrict__ cent,
                                             float* __restrict__ out,
                                             double* __restrict__ csq64,
                                             const int* __restrict__ midx,
                                             int* __restrict__ hist) {
  const int b = blockIdx.x;              // 512 blocks
  const int m = b >> 6;
  const int cg = (b >> 2) & 15;
  const int q = b & 3;
  const int tid = threadIdx.x;
  const int row = tid >> 3;              // 0..31 cluster within group
  const int o = tid & 7;                 // 0..7 eighth of the quarter
  const int gk0 = q * 32 + o * 4;
  const int B32 = (m * 16 + cg) * 32;
  const float* src = cent + ((size_t)(m * K_CLUST + cg * 32 + row)) * E_DIM;
  double ss = 0.0;
#pragma unroll
  for (int j = 0; j < 4; ++j) {
    const int gk = gk0 + j;
    const float4 a = *(const float4*)(src + gk * 8);
    const float4 bb = *(const float4*)(src + gk * 8 + 4);
    ss += (double)a.x * a.x + (double)a.y * a.y + (double)a.z * a.z +
          (double)a.w * a.w + (double)bb.x * bb.x + (double)bb.y * bb.y +
          (double)bb.z * bb.z + (double)bb.w * bb.w;
    const size_t foff = (size_t)(B32 + (gk >> 2)) * 1024 + 512 +
                        ((gk & 3) * 32 + row) * 4;
    *(bf16x8*)(out + foff) = cvt8(a, bb);
  }
  __shared__ double csq_l[32][8];
  csq_l[row][o] = ss;
  __syncthreads();
  if (tid < 32) {
    double s = 0.0;
#pragma unroll
    for (int t = 0; t < 8; ++t) s += csq_l[tid][t];
    atomicAdd(&csq64[m * K_CLUST + cg * 32 + tid], s);
  }
  // ---- fused per-segment model histogram (blocks 0..63 only) ----
  if (b < 64) {
    __shared__ int h[M_MODELS * 33];
    for (int i = tid; i < M_MODELS * 33; i += 256) h[i] = 0;
    __syncthreads();
    const int mm = midx[b * 256 + tid];
    atomicAdd(&h[mm * 33 + (tid & 31)], 1);
    __syncthreads();
    if (tid < M_MODELS) {
      int s = 0;
      for (int j = 0; j < 32; ++j) s += h[tid * 33 + j];
      hist[b * M_MODELS + tid] = s;
    }
  }
}

// ---------------- K2: scatter frames into per-model buckets ----------------
__global__ __launch_bounds__(256) void k_scatter(const int* __restrict__ midx,
                                                 const int* __restrict__ hist,
                                                 int* __restrict__ order,
                                                 int* __restrict__ offs) {
  __shared__ int h2[64 * M_MODELS];
  __shared__ int cur[M_MODELS];
  const int tid = threadIdx.x;
  h2[tid] = hist[tid];
  h2[tid + 256] = hist[tid + 256];
  __syncthreads();
  if (tid < M_MODELS) {
    int tot_before = 0;
    for (int mp = 0; mp < tid; ++mp)
      for (int b = 0; b < 64; ++b) tot_before += h2[b * M_MODELS + mp];
    int prior = 0;
    for (int b = 0; b < (int)blockIdx.x; ++b) prior += h2[b * M_MODELS + tid];
    cur[tid] = tot_before + prior;
  }
  if (blockIdx.x == 0 && tid <= M_MODELS) {
    int o = 0;
    for (int mp = 0; mp < tid; ++mp)
      for (int b = 0; b < 64; ++b) o += h2[b * M_MODELS + mp];
    offs[tid] = o;
  }
  __syncthreads();
  const int f = blockIdx.x * 256 + tid;
  const int pos = atomicAdd(&cur[midx[f]], 1);
  order[pos] = f;
}

// ---------------- K3: fused scores + argmin + recheck -> code/output -------
// Block: 8 waves (512 thr), tile = 32 frames x 512 cols; wave w -> cols
// [w*64, w*64+64). acc: 2 x 32x32 tiles. A: LDS chunks of 128 k, double-
// buffered, COALESCED staging (16 thr/row, 2 consecutive float4 each),
// granule stride padded to 33 rows (16.9 KB). B: swizzled bf16 (d_out
// rows 0..4095 high halves), depth-8 register ring.
// grid = (M, 80): linear id % 8 == m -> per-model XCD affinity.
// Resolution: t>=4096 -> direct row write; t<4096 -> park code at col 0.
__global__ __launch_bounds__(512, 2) void k_dist(const float* __restrict__ emb,
                                                 const float* __restrict__ cent,
                                                 const double* __restrict__ csq64,
                                                 const int* __restrict__ order,
                                                 const int* __restrict__ offs,
                                                 float* __restrict__ out) {
  const int m = blockIdx.x;
  const int o0 = offs[m];
  const int cnt = offs[m + 1] - o0;
  const int start = blockIdx.y * FPB;
  if (start >= cnt) return;
  const int nvalid = min(FPB, cnt - start);

  __shared__ __align__(16) __bf16 A_l[2 * 16 * ROWP * 8];  // 16.9 KB
  __shared__ int rows_l[FPB];
  __shared__ float wmin_s[8][FPB];
  __shared__ int wcol_s[8][FPB];
  __shared__ float gmin_s[FPB];
  __shared__ int cnt_s[FPB];
  __shared__ int cand_s[FPB][32];

  const int tid = threadIdx.x;
  const int l = tid & 63;
  const int w = tid >> 6;          // 0..7
  const int ln = l & 31;
  const int lh = l >> 5;

  if (tid < FPB) rows_l[tid] = order[o0 + start + min(tid, nvalid - 1)];
  __syncthreads();

  // A staging role (COALESCED): thread -> row (tid>>4), 32B slice (tid&15).
  // 16 lanes cover one row's 512B chunk contiguously.
  const int s_row = tid >> 4;                    // 0..31
  const int s_o = tid & 15;                      // 0..15 = granule index
  const float4* emb4 = (const float4*)emb;
  const size_t arow4 = (size_t)rows_l[s_row] * (E_DIM / 4);

  float4 pa[2];
  pa[0] = emb4[arow4 + s_o * 2 + 0];
  pa[1] = emb4[arow4 + s_o * 2 + 1];
  *(bf16x8*)(A_l + ((s_o)*ROWP + s_row) * 8) = cvt8(pa[0], pa[1]);

  // B base pointers (swizzled bf16 region in d_out); wave w -> cg {2w, 2w+1}
  const char* bbase[2];
#pragma unroll
  for (int ct = 0; ct < 2; ++ct) {
    const int cg = w * 2 + ct;
    bbase[ct] = (const char*)out + (size_t)(m * 16 + cg) * 131072 + 2048 + l * 16;
  }
#define LOADB(ct, kb) (*(const bf16x8*)(bbase[ct] + (((kb) >> 1) << 12) + (((kb) & 1) << 10)))

  bf16x8 bR[8][2];                               // depth-8 ring
#pragma unroll
  for (int d = 0; d < 8; ++d)
#pragma unroll
    for (int ct = 0; ct < 2; ++ct) bR[d][ct] = LOADB(ct, d);

  floatx16 acc[2] = {};

  for (int c = 0; c < NCH; ++c) {
    __syncthreads();                             // A buf (c&1) ready
    const int buf = (c & 1) * 16;
    if (c + 1 < NCH) {
      pa[0] = emb4[arow4 + (c + 1) * 32 + s_o * 2 + 0];
      pa[1] = emb4[arow4 + (c + 1) * 32 + s_o * 2 + 1];
    }
#pragma unroll
    for (int jj = 0; jj < 8; ++jj) {
      const int kb = c * 8 + jj;
      const int p = kb & 7;
      const bf16x8 a0 = *(const bf16x8*)(A_l + ((buf + jj * 2 + lh) * ROWP + ln) * 8);
      acc[0] = __builtin_amdgcn_mfma_f32_32x32x16_bf16(a0, bR[p][0], acc[0], 0, 0, 0);
      acc[1] = __builtin_amdgcn_mfma_f32_32x32x16_bf16(a0, bR[p][1], acc[1], 0, 0, 0);
      if (kb + 8 < 64) {
        bR[p][0] = LOADB(0, kb + 8);
        bR[p][1] = LOADB(1, kb + 8);
      }
    }
    if (c + 1 < NCH) {                           // write other buffer
      const int nbuf = ((c + 1) & 1) * 16;
      *(bf16x8*)(A_l + ((nbuf + s_o) * ROWP + s_row) * 8) = cvt8(pa[0], pa[1]);
    }
  }
#undef LOADB

  // ---- per-wave argmin (scores s = csq - 2*dot stay in regs) ----
  float cs[2];
#pragma unroll
  for (int ct = 0; ct < 2; ++ct)
    cs[ct] = (float)csq64[m * K_CLUST + w * 64 + ct * 32 + ln];

#pragma unroll
  for (int r = 0; r < 16; ++r) {
    const int fr = (r & 3) + 8 * (r >> 2) + 4 * lh;
    float bm = cs[0] - 2.0f * acc[0][r];
    int bc = w * 64 + ln;
    {
      const float s = cs[1] - 2.0f * acc[1][r];
      if (s < bm) { bm = s; bc = w * 64 + 32 + ln; }
    }
#pragma unroll
    for (int sh = 1; sh <= 16; sh <<= 1) {       // reduce within lane-half
      const float om = __shfl_xor(bm, sh, 64);
      const int oc = __shfl_xor(bc, sh, 64);
      if (om < bm || (om == bm && oc < bc)) { bm = om; bc = oc; }
    }
    if (ln == 0) { wmin_s[w][fr] = bm; wcol_s[w][fr] = bc; }
  }
  __syncthreads();

  if (tid < FPB) {                               // cross-wave min
    float g = wmin_s[0][tid];
    int gc = wcol_s[0][tid];
#pragma unroll
    for (int w2 = 1; w2 < 8; ++w2) {
      const float v = wmin_s[w2][tid];
      const int vc = wcol_s[w2][tid];
      if (v < g || (v == g && vc < gc)) { g = v; gc = vc; }
    }
    gmin_s[tid] = g;
    cnt_s[tid] = 0;
  }
  __syncthreads();

  // ---- candidate collection within eps = 3.0 ----
#pragma unroll
  for (int r = 0; r < 16; ++r) {
    const int fr = (r & 3) + 8 * (r >> 2) + 4 * lh;
    const float thr = gmin_s[fr] + 3.0f;
#pragma unroll
    for (int ct = 0; ct < 2; ++ct) {
      const float s = cs[ct] - 2.0f * acc[ct][r];
      if (s < thr) {
        const int ix = atomicAdd(&cnt_s[fr], 1);
        if (ix < 32) cand_s[fr][ix] = w * 64 + ct * 32 + ln;
      }
    }
  }
  __syncthreads();

  // ---- resolution: wave w -> frames w*4 .. w*4+3; exact fp64 recheck ----
  for (int i = 0; i < 4; ++i) {
    const int f = w * 4 + i;
    const int t = rows_l[f];
    const int n = min(cnt_s[f], 32);
    int code;
    if (n == 1) {
      code = cand_s[f][0];
    } else {
      float4 xv[4];
#pragma unroll
      for (int q = 0; q < 4; ++q)
        xv[q] = *(const float4*)(emb + (size_t)t * E_DIM + (q * 64 + l) * 4);
      double bd = 1e300;
      int bi = 1 << 30;
      for (int j = 0; j < n; ++j) {
        const int cc = cand_s[f][j];
        const float4* crow4 = (const float4*)(cent + ((size_t)(m * K_CLUST + cc)) * E_DIM);
        double s = 0.0;
#pragma unroll
        for (int q = 0; q < 4; ++q) {
          const float4 cv = crow4[q * 64 + l];
          s += (double)xv[q].x * cv.x + (double)xv[q].y * cv.y +
               (double)xv[q].z * cv.z + (double)xv[q].w * cv.w;
        }
#pragma unroll
        for (int sh = 32; sh >= 1; sh >>= 1) s += __shfl_xor(s, sh, 64);
        const double d = csq64[m * K_CLUST + cc] - 2.0 * s;
        if (d < bd || (d == bd && cc < bi)) { bd = d; bi = cc; }
      }
      code = bi;
    }
    if (t >= 4096) {
      // rows >= 4096 never hold B panels: write the output row directly.
      const float4* crow = (const float4*)(cent + ((size_t)(m * K_CLUST + code)) * E_DIM);
      float4* drow = (float4*)(out + (size_t)t * E_DIM);
#pragma unroll
      for (int q = 0; q < 4; ++q) drow[q * 64 + l] = crow[q * 64 + l];
    } else if (l == 0) {
      *(int*)(out + (size_t)t * E_DIM) = code;   // col 0: no B overlap
    }
  }
}

// ---------------- K4: expand parked codes (t < 4096) -> output rows --------
__global__ __launch_bounds__(256) void k_gather(const float* __restrict__ cent,
                                                const int* __restrict__ midx,
                                                float* __restrict__ out) {
  const int t = blockIdx.x * 4 + (threadIdx.x >> 6);   // t in [0, 4096)
  const int l = threadIdx.x & 63;
  float* drow = out + (size_t)t * E_DIM;
  const int code = *(const int*)drow;            // read before overwrite (dep-ordered)
  const int m = midx[t];
  const float4* src = (const float4*)(cent + ((size_t)(m * K_CLUST + code)) * E_DIM);
  float4* dst = (float4*)drow;
#pragma unroll
  for (int q = 0; q < 4; ++q) dst[q * 64 + l] = src[q * 64 + l];
}

extern "C" void kernel_launch(void* const* d_in, const int* in_sizes, int n_in,
                              void* d_out, int out_size, void* d_ws, size_t ws_size,
                              hipStream_t stream) {
  const float* emb = (const float*)d_in[0];     // [1,T,E] fp32
  const float* cent = (const float*)d_in[1];    // [M,K,E] fp32
  const int* midx = (const int*)d_in[2];        // [T] int32
  float* out = (float*)d_out;                   // [1,T,E] fp32

  char* ws = (char*)d_ws;                       // ~100 KB
  double* csq64 = (double*)(ws + 0);
  int* hist = (int*)(ws + 32768);
  int* offs = (int*)(ws + 34816);
  int* order = (int*)(ws + 34880);

  (void)hipMemsetAsync(csq64, 0, M_MODELS * K_CLUST * sizeof(double), stream);
  hipLaunchKernelGGL(k_cvt, dim3(512), dim3(256), 0, stream,
                     cent, out, csq64, midx, hist);
  hipLaunchKernelGGL(k_scatter, dim3(64), dim3(256), 0, stream, midx, hist, order, offs);
  hipLaunchKernelGGL(k_dist, dim3(M_MODELS, 80), dim3(512), 0, stream,
                     emb, cent, csq64, order, offs, out);
  hipLaunchKernelGGL(k_gather, dim3(4096 / 4), dim3(256), 0, stream,
                     cent, midx, out);
}